// Round 3
// baseline (98.099 us; speedup 1.0000x reference)
//
#include <hip/hip_runtime.h>
#include <math.h>

#define FFT_LEN   1024
#define STEP      256
#define NFRAMES   8192
#define OUT_LEN   (STEP * (NFRAMES - 1) + FFT_LEN)   // 2097920
#define NVEC      (OUT_LEN / 4)                      // 524480 float4 outputs
#define NBLK      1025
#define VSTRIDE   (NBLK * 256)                       // 262400 vecs; *4 samples = 1049600 = 4100 frames
#define QSHIFT    4100                               // frame offset between the two halves
#define ELEMSHIFT (QSHIFT * FFT_LEN)                 // 4198400 input elems between halves

typedef float f32x4 __attribute__((ext_vector_type(4)));

__global__ __launch_bounds__(256) void istft_ola_kernel(
    const float* __restrict__ Sr,
    const float* __restrict__ Si,
    float* __restrict__ out)
{
    const float inv_n  = 1.0f / 1024.0f;
    const float two_pi = 6.283185307179586f;

    const int v0 = (int)blockIdx.x * 256 + (int)threadIdx.x;
    const int t0 = v0 << 2;
    const int m0 = t0 & (STEP - 1);                  // same for both halves
    const int q0 = t0 >> 8;                          // wave-uniform (64 consecutive v0 share q0)

    // Trig for arm 0's four bins; arms 1..3 by quarter-turn identities.
    float c[4], s[4];
#pragma unroll
    for (int d = 0; d < 4; ++d) {
        float theta = two_pi * (float)(m0 + d) * inv_n;
        sincosf(theta, &s[d], &c[d]);
    }
    float A[4][4], B[4][4], W[4][4];
#pragma unroll
    for (int d = 0; d < 4; ++d) {
        const float cc = c[d], ss = s[d];
#pragma unroll
        for (int a = 0; a < 4; ++a) {
            const float ca = (a == 0) ? cc : (a == 1) ? -ss : (a == 2) ? -cc : ss;
            const float sa = (a == 0) ? ss : (a == 1) ? cc  : (a == 2) ? -ss : -cc;
            const float w  = 0.5f - 0.5f * ca;
            A[a][d] = (ca - sa) * w * inv_n;
            B[a][d] = (ca + sa) * w * inv_n;
            W[a][d] = w;
        }
    }

    if (q0 >= 3 && q0 <= 4091) {
        // Both halves interior (all 4 arms valid, Hann COLA sum == 2 exactly).
        // Issue all 16 nontemporal loads before any FMA -> 16-deep MLP per wave.
        f32x4 R0[4], I0[4], R1[4], I1[4];
#pragma unroll
        for (int a = 0; a < 4; ++a) {
            const int base0 = (q0 - a) * FFT_LEN + (m0 + a * STEP);
            const int base1 = base0 + ELEMSHIFT;
            R0[a] = __builtin_nontemporal_load((const f32x4*)(Sr + base0));
            I0[a] = __builtin_nontemporal_load((const f32x4*)(Si + base0));
            R1[a] = __builtin_nontemporal_load((const f32x4*)(Sr + base1));
            I1[a] = __builtin_nontemporal_load((const f32x4*)(Si + base1));
        }
        f32x4 n0 = (f32x4)(0.f), n1 = (f32x4)(0.f);
#pragma unroll
        for (int a = 0; a < 4; ++a) {
#pragma unroll
            for (int d = 0; d < 4; ++d) {
                n0[d] = fmaf(R0[a][d], A[a][d], fmaf(-I0[a][d], B[a][d], n0[d]));
                n1[d] = fmaf(R1[a][d], A[a][d], fmaf(-I1[a][d], B[a][d], n1[d]));
            }
        }
        n0 *= 0.5f;
        n1 *= 0.5f;
        __builtin_nontemporal_store(n0, (f32x4*)(out + t0));
        __builtin_nontemporal_store(n1, (f32x4*)(out + t0 + VSTRIDE * 4));
    } else {
        // General path: per-half existence, per-arm validity, true divide.
#pragma unroll
        for (int half = 0; half < 2; ++half) {
            const int v = v0 + half * VSTRIDE;
            if (v >= NVEC) break;
            const int t = v << 2;
            const int q = t >> 8;

            float num[4] = {0.f, 0.f, 0.f, 0.f};
            float den[4] = {0.f, 0.f, 0.f, 0.f};
#pragma unroll
            for (int a = 0; a < 4; ++a) {
                const int i = q - a;
                if ((unsigned)i < (unsigned)NFRAMES) {
                    const int base = i * FFT_LEN + (m0 + a * STEP);
                    const f32x4 R = *(const f32x4*)(Sr + base);
                    const f32x4 I = *(const f32x4*)(Si + base);
#pragma unroll
                    for (int d = 0; d < 4; ++d) {
                        num[d] = fmaf(R[d], A[a][d], fmaf(-I[d], B[a][d], num[d]));
                        den[d] += W[a][d];
                    }
                }
            }
            f32x4 o;
#pragma unroll
            for (int d = 0; d < 4; ++d)
                o[d] = num[d] / fmaxf(den[d], 1e-8f);
            *(f32x4*)(out + t) = o;
        }
    }
}

extern "C" void kernel_launch(void* const* d_in, const int* in_sizes, int n_in,
                              void* d_out, int out_size, void* d_ws, size_t ws_size,
                              hipStream_t stream) {
    const float* Sr = (const float*)d_in[0];
    const float* Si = (const float*)d_in[1];
    float* out = (float*)d_out;
    (void)in_sizes; (void)n_in; (void)out_size; (void)d_ws; (void)ws_size;

    dim3 block(256);
    dim3 grid(NBLK);
    istft_ola_kernel<<<grid, block, 0, stream>>>(Sr, Si, out);
}

// Round 6
// 94.631 us; speedup vs baseline: 1.0366x; 1.0366x over previous
//
#include <hip/hip_runtime.h>
#include <math.h>

#define FFT_LEN   1024
#define STEP      256
#define NFRAMES   8192
#define OUT_LEN   (STEP * (NFRAMES - 1) + FFT_LEN)   // 2097920
#define NVEC      (OUT_LEN / 4)                      // 524480 float4 outputs
#define NBLK      1025
#define VSTRIDE   (NBLK * 256)                       // 262400 vecs; *4 samples = 1049600 = 4100 frames
#define QSHIFT    4100                               // frame offset between the two halves
#define ELEMSHIFT (QSHIFT * FFT_LEN)                 // 4198400 input elems between halves

typedef float f32x4 __attribute__((ext_vector_type(4)));

__global__ __launch_bounds__(256) void istft_ola_kernel(
    const float* __restrict__ Sr,
    const float* __restrict__ Si,
    float* __restrict__ out)
{
    const float inv_n  = 1.0f / 1024.0f;
    const float two_pi = 6.283185307179586f;

    const int v0 = (int)blockIdx.x * 256 + (int)threadIdx.x;
    const int t0 = v0 << 2;
    const int m0 = t0 & (STEP - 1);                  // same for both halves
    const int q0 = t0 >> 8;                          // wave-uniform (64 consecutive v0 share q0)

    // Trig for arm 0's four bins; arms 1..3 by quarter-turn identities.
    float c[4], s[4];
#pragma unroll
    for (int d = 0; d < 4; ++d) {
        float theta = two_pi * (float)(m0 + d) * inv_n;
        sincosf(theta, &s[d], &c[d]);
    }
    float A[4][4], B[4][4], W[4][4];
#pragma unroll
    for (int d = 0; d < 4; ++d) {
        const float cc = c[d], ss = s[d];
#pragma unroll
        for (int a = 0; a < 4; ++a) {
            const float ca = (a == 0) ? cc : (a == 1) ? -ss : (a == 2) ? -cc : ss;
            const float sa = (a == 0) ? ss : (a == 1) ? cc  : (a == 2) ? -ss : -cc;
            const float w  = 0.5f - 0.5f * ca;
            A[a][d] = (ca - sa) * w * inv_n;
            B[a][d] = (ca + sa) * w * inv_n;
            W[a][d] = w;
        }
    }

    if (q0 >= 3 && q0 <= 4091) {
        // Both halves interior (all 4 arms valid, Hann COLA sum == 2 exactly).
        // Batch all 16 loads before the FMA stream (16-deep vmcnt MLP per wave).
        f32x4 R0[4], I0[4], R1[4], I1[4];
#pragma unroll
        for (int a = 0; a < 4; ++a) {
            const int base0 = (q0 - a) * FFT_LEN + (m0 + a * STEP);
            const int base1 = base0 + ELEMSHIFT;
            R0[a] = *(const f32x4*)(Sr + base0);
            I0[a] = *(const f32x4*)(Si + base0);
            R1[a] = *(const f32x4*)(Sr + base1);
            I1[a] = *(const f32x4*)(Si + base1);
        }
        f32x4 n0 = (f32x4)(0.f), n1 = (f32x4)(0.f);
#pragma unroll
        for (int a = 0; a < 4; ++a) {
#pragma unroll
            for (int d = 0; d < 4; ++d) {
                n0[d] = fmaf(R0[a][d], A[a][d], fmaf(-I0[a][d], B[a][d], n0[d]));
                n1[d] = fmaf(R1[a][d], A[a][d], fmaf(-I1[a][d], B[a][d], n1[d]));
            }
        }
        n0 *= 0.5f;
        n1 *= 0.5f;
        *(f32x4*)(out + t0) = n0;
        *(f32x4*)(out + t0 + VSTRIDE * 4) = n1;
    } else {
        // General path: per-half existence, per-arm validity, true divide.
#pragma unroll
        for (int half = 0; half < 2; ++half) {
            const int v = v0 + half * VSTRIDE;
            if (v >= NVEC) break;
            const int t = v << 2;
            const int q = t >> 8;

            float num[4] = {0.f, 0.f, 0.f, 0.f};
            float den[4] = {0.f, 0.f, 0.f, 0.f};
#pragma unroll
            for (int a = 0; a < 4; ++a) {
                const int i = q - a;
                if ((unsigned)i < (unsigned)NFRAMES) {
                    const int base = i * FFT_LEN + (m0 + a * STEP);
                    const f32x4 R = *(const f32x4*)(Sr + base);
                    const f32x4 I = *(const f32x4*)(Si + base);
#pragma unroll
                    for (int d = 0; d < 4; ++d) {
                        num[d] = fmaf(R[d], A[a][d], fmaf(-I[d], B[a][d], num[d]));
                        den[d] += W[a][d];
                    }
                }
            }
            f32x4 o;
#pragma unroll
            for (int d = 0; d < 4; ++d)
                o[d] = num[d] / fmaxf(den[d], 1e-8f);
            *(f32x4*)(out + t) = o;
        }
    }
}

extern "C" void kernel_launch(void* const* d_in, const int* in_sizes, int n_in,
                              void* d_out, int out_size, void* d_ws, size_t ws_size,
                              hipStream_t stream) {
    const float* Sr = (const float*)d_in[0];
    const float* Si = (const float*)d_in[1];
    float* out = (float*)d_out;
    (void)in_sizes; (void)n_in; (void)out_size; (void)d_ws; (void)ws_size;

    dim3 block(256);
    dim3 grid(NBLK);
    istft_ola_kernel<<<grid, block, 0, stream>>>(Sr, Si, out);
}

// Round 7
// 92.644 us; speedup vs baseline: 1.0589x; 1.0215x over previous
//
#include <hip/hip_runtime.h>
#include <math.h>

#define FFT_LEN   1024
#define STEP      256
#define NFRAMES   8192
#define OUT_LEN   (STEP * (NFRAMES - 1) + FFT_LEN)   // 2097920
#define NVEC      (OUT_LEN / 4)                      // 524480 float4 outputs
#define NBLK      1025
#define VSTRIDE   (NBLK * 256)                       // 262400; (VSTRIDE*4) % 256 == 0 -> same m0

__global__ __launch_bounds__(256) void istft_ola_kernel(
    const float* __restrict__ Sr,
    const float* __restrict__ Si,
    float* __restrict__ out)
{
    const float inv_n  = 1.0f / 1024.0f;
    const float two_pi = 6.283185307179586f;

    const int v0 = (int)blockIdx.x * 256 + (int)threadIdx.x;
    const int m0 = (v0 << 2) & (STEP - 1);           // same for both vecs this thread handles

    // Trig only for arm 0's four bins; arms 1..3 via quarter-turn identities.
    float c[4], s[4];
#pragma unroll
    for (int d = 0; d < 4; ++d) {
        float theta = two_pi * (float)(m0 + d) * inv_n;
        sincosf(theta, &s[d], &c[d]);
    }

    // A[a][d] = (c_a - s_a)*w_a/n ; B[a][d] = (c_a + s_a)*w_a/n ; w_a = 0.5 - 0.5*c_a
    // (c_a, s_a): a=0:(c,s)  a=1:(-s,c)  a=2:(-c,-s)  a=3:(s,-c)
    float A[4][4], B[4][4], W[4][4];
#pragma unroll
    for (int d = 0; d < 4; ++d) {
        const float cc = c[d], ss = s[d];
#pragma unroll
        for (int a = 0; a < 4; ++a) {
            const float ca = (a == 0) ? cc : (a == 1) ? -ss : (a == 2) ? -cc : ss;
            const float sa = (a == 0) ? ss : (a == 1) ? cc  : (a == 2) ? -ss : -cc;
            const float w  = 0.5f - 0.5f * ca;
            A[a][d] = (ca - sa) * w * inv_n;
            B[a][d] = (ca + sa) * w * inv_n;
            W[a][d] = w;
        }
    }

#pragma unroll
    for (int half = 0; half < 2; ++half) {
        const int v = v0 + half * VSTRIDE;
        if (half == 1 && v >= NVEC) break;

        const int t0 = v << 2;
        const int q  = t0 >> 8;                      // wave-uniform

        float num[4] = {0.f, 0.f, 0.f, 0.f};

        if (q >= 3 && q <= NFRAMES - 1) {
            // Interior: all 4 arms valid, Hann COLA sum == 2.0 exactly.
#pragma unroll
            for (int a = 0; a < 4; ++a) {
                const size_t base = (size_t)(q - a) * FFT_LEN + (size_t)(m0 + a * STEP);
                const float4 R = *reinterpret_cast<const float4*>(Sr + base);
                const float4 I = *reinterpret_cast<const float4*>(Si + base);
                num[0] = fmaf(R.x, A[a][0], fmaf(-I.x, B[a][0], num[0]));
                num[1] = fmaf(R.y, A[a][1], fmaf(-I.y, B[a][1], num[1]));
                num[2] = fmaf(R.z, A[a][2], fmaf(-I.z, B[a][2], num[2]));
                num[3] = fmaf(R.w, A[a][3], fmaf(-I.w, B[a][3], num[3]));
            }
            float4 o;
            o.x = num[0] * 0.5f;
            o.y = num[1] * 0.5f;
            o.z = num[2] * 0.5f;
            o.w = num[3] * 0.5f;
            *reinterpret_cast<float4*>(out + t0) = o;
        } else {
            // Edge: per-arm validity + true window-correction divide.
            float den[4] = {0.f, 0.f, 0.f, 0.f};
#pragma unroll
            for (int a = 0; a < 4; ++a) {
                const int i = q - a;
                if ((unsigned)i < (unsigned)NFRAMES) {
                    const size_t base = (size_t)i * FFT_LEN + (size_t)(m0 + a * STEP);
                    const float4 R = *reinterpret_cast<const float4*>(Sr + base);
                    const float4 I = *reinterpret_cast<const float4*>(Si + base);
                    num[0] = fmaf(R.x, A[a][0], fmaf(-I.x, B[a][0], num[0]));
                    num[1] = fmaf(R.y, A[a][1], fmaf(-I.y, B[a][1], num[1]));
                    num[2] = fmaf(R.z, A[a][2], fmaf(-I.z, B[a][2], num[2]));
                    num[3] = fmaf(R.w, A[a][3], fmaf(-I.w, B[a][3], num[3]));
                    den[0] += W[a][0];
                    den[1] += W[a][1];
                    den[2] += W[a][2];
                    den[3] += W[a][3];
                }
            }
            float4 o;
            o.x = num[0] / fmaxf(den[0], 1e-8f);
            o.y = num[1] / fmaxf(den[1], 1e-8f);
            o.z = num[2] / fmaxf(den[2], 1e-8f);
            o.w = num[3] / fmaxf(den[3], 1e-8f);
            *reinterpret_cast<float4*>(out + t0) = o;
        }
    }
}

extern "C" void kernel_launch(void* const* d_in, const int* in_sizes, int n_in,
                              void* d_out, int out_size, void* d_ws, size_t ws_size,
                              hipStream_t stream) {
    const float* Sr = (const float*)d_in[0];
    const float* Si = (const float*)d_in[1];
    float* out = (float*)d_out;
    (void)in_sizes; (void)n_in; (void)out_size; (void)d_ws; (void)ws_size;

    dim3 block(256);
    dim3 grid(NBLK);   // each block handles chunks b and b+1025 (same m0 -> shared trig)
    istft_ola_kernel<<<grid, block, 0, stream>>>(Sr, Si, out);
}